// Round 4
// baseline (353.310 us; speedup 1.0000x reference)
//
#include <hip/hip_runtime.h>
#include <hip/hip_bf16.h>

#define THREADS 256
#define MTILE   32      // batch rows per block
#define HID     128
#define BATCH   32768
#define NFEAT   8

typedef __attribute__((ext_vector_type(4))) float f32x4;
typedef __attribute__((ext_vector_type(8))) short s16x8;

typedef unsigned int __attribute__((address_space(1))) as1_u32;
typedef unsigned int __attribute__((address_space(3))) as3_u32;

struct Ptrs {
    const float* feat[NFEAT];
    const float* wk[NFEAT];
    const float* wv[NFEAT];
    const float* q;
};

__device__ __forceinline__ unsigned short f2bf(float f) {
    union { __hip_bfloat16 h; unsigned short u; } c; c.h = __float2bfloat16(f); return c.u;
}

// async global->LDS DMA, 16B per lane; LDS dest is wave-uniform base + lane*16
__device__ __forceinline__ void dma16(const float* g, float* l) {
    __builtin_amdgcn_global_load_lds((const as1_u32*)g, (as3_u32*)l, 16, 0, 0);
}

__device__ const int g_fdim[NFEAT] = {32, 64, 96, 128, 192, 256, 384, 512};
__device__ const int g_foff[NFEAT] = {0, 32, 96, 192, 320, 512, 768, 1152};

// ---------------- prep 1: qk_i = (Wk_i^T q) / sqrt(128) ----------------
__global__ void prep_qk(Ptrs p, float* qk) {
    int i = blockIdx.x;
    int d = g_fdim[i];
    const float* Wk = p.wk[i];
    const float* q  = p.q;
    for (int c = threadIdx.x; c < d; c += blockDim.x) {
        float s = 0.f;
        #pragma unroll 8
        for (int h = 0; h < HID; ++h) s = fmaf(q[h], Wk[h * d + c], s);
        qk[g_foff[i] + c] = s * 0.08838834764831845f;   // 1/sqrt(128)
    }
}

// ---------------- prep 2: Wv -> bf16 in B-fragment layout ----------------
// WvB[128*foff[fi] + (kg*128 + h)*8 + j] = bf16(Wv[h*D + kg*8 + j])
__global__ void prep_wv(Ptrs p, unsigned short* WvB) {
    int fi    = blockIdx.x >> 3;
    int slice = blockIdx.x & 7;
    int D  = g_fdim[fi];
    int Dg = D >> 3;
    const float* Wv = p.wv[fi];
    unsigned short* out = WvB + 128 * g_foff[fi];
    int h0  = slice * 16;
    int cnt = 16 * Dg;
    for (int e = threadIdx.x; e < cnt; e += blockDim.x) {
        int h  = h0 + e / Dg;
        int kg = e - (e / Dg) * Dg;
        const float* src = Wv + h * D + kg * 8;
        float4 x = *reinterpret_cast<const float4*>(src);
        float4 y = *reinterpret_cast<const float4*>(src + 4);
        s16x8 b;
        b[0] = (short)f2bf(x.x); b[1] = (short)f2bf(x.y);
        b[2] = (short)f2bf(x.z); b[3] = (short)f2bf(x.w);
        b[4] = (short)f2bf(y.x); b[5] = (short)f2bf(y.y);
        b[6] = (short)f2bf(y.z); b[7] = (short)f2bf(y.w);
        *reinterpret_cast<s16x8*>(out + (kg * 128 + h) * 8) = b;
    }
}

// ---------------- stage: DMA a 32 x DC fp32 chunk into LDS (swizzled) ----------------
// LDS is flat lane-order (DMA requirement). Logical (r, col): physical 32B-group
// g_phys = g_log ^ (r & MASK), implemented by permuting the GLOBAL address per lane.
template<int FI, int D, int CK0, int DC, int MASK>
__device__ __forceinline__ void stage(const Ptrs& p, int row0, int tid, float* buf) {
    const float* fp = p.feat[FI];
    constexpr int NIT = DC / 32;    // 16B units: 32*DC*4/16 = 8*DC ; per iter 256 lanes
    #pragma unroll
    for (int it = 0; it < NIT; ++it) {
        int e4 = it * THREADS + tid;          // 16B unit index
        int e  = e4 * 4;                      // fp32 element index (flat, physical)
        int r  = e / DC;
        int cp = e - r * DC;                  // physical col (multiple of 4)
        int gl = (cp >> 3) ^ (r & MASK);      // logical 32B group
        int col = CK0 + gl * 8 + (cp & 7);
        dma16(fp + (size_t)(row0 + r) * D + col, buf + e);
    }
}

// ---------------- compute one chunk from LDS ----------------
template<int FI, int FOFF, int CK0, int DC, int MASK, bool FIRST, bool LAST>
__device__ __forceinline__ void compute_chunk(
    const float* buf, const unsigned short* WvB, const float* qk,
    float* wAll, float& spart, f32x4 (&P)[2][2],
    int tid, int wave, int l15, int q4)
{
    if (FIRST) {
        spart = 0.f;
        #pragma unroll
        for (int mt = 0; mt < 2; ++mt) {
            P[mt][0] = f32x4{0.f, 0.f, 0.f, 0.f};
            P[mt][1] = f32x4{0.f, 0.f, 0.f, 0.f};
        }
    }

    // ---- score partial: 8 threads per row, fp32 from LDS ----
    {
        int r = tid >> 3, part = tid & 7;
        constexpr int G = DC / 8;
        float acc = 0.f;
        #pragma unroll
        for (int gi = 0; gi < G; gi += 8) {
            int g = gi + part;
            if (g < G) {
                int gp = g ^ (r & MASK);
                const float* a = buf + r * DC + gp * 8;
                float4 u0 = *reinterpret_cast<const float4*>(a);
                float4 u1 = *reinterpret_cast<const float4*>(a + 4);
                const float* qf = qk + FOFF + CK0 + g * 8;
                float4 q0 = *reinterpret_cast<const float4*>(qf);
                float4 q1 = *reinterpret_cast<const float4*>(qf + 4);
                acc += u0.x*q0.x + u0.y*q0.y + u0.z*q0.z + u0.w*q0.w
                     + u1.x*q1.x + u1.y*q1.y + u1.z*q1.z + u1.w*q1.w;
            }
        }
        spart += acc;
    }

    // ---- MFMA: P += A @ Wv^T (A fp32 LDS -> bf16 inline; B pre-packed bf16) ----
    {
        int hb = wave * 32 + l15;
        #pragma unroll
        for (int kk = 0; kk < DC / 32; ++kk) {
            int kgG = CK0 / 8 + kk * 4 + q4;          // feature-local k-group for B
            const unsigned short* bb = WvB + 128 * FOFF + ((size_t)kgG * 128 + hb) * 8;
            s16x8 b0 = *reinterpret_cast<const s16x8*>(bb);
            s16x8 b1 = *reinterpret_cast<const s16x8*>(bb + 128);
            int glA = kk * 4 + q4;                    // chunk-local logical k-group
            #pragma unroll
            for (int mt = 0; mt < 2; ++mt) {
                int m = mt * 16 + l15;
                int gp = glA ^ (m & MASK);
                const float* a = buf + m * DC + gp * 8;
                float4 x = *reinterpret_cast<const float4*>(a);
                float4 y = *reinterpret_cast<const float4*>(a + 4);
                s16x8 af;
                af[0] = (short)f2bf(x.x); af[1] = (short)f2bf(x.y);
                af[2] = (short)f2bf(x.z); af[3] = (short)f2bf(x.w);
                af[4] = (short)f2bf(y.x); af[5] = (short)f2bf(y.y);
                af[6] = (short)f2bf(y.z); af[7] = (short)f2bf(y.w);
                P[mt][0] = __builtin_amdgcn_mfma_f32_16x16x32_bf16(af, b0, P[mt][0], 0, 0, 0);
                P[mt][1] = __builtin_amdgcn_mfma_f32_16x16x32_bf16(af, b1, P[mt][1], 0, 0, 0);
            }
        }
    }

    if (LAST) {  // finalize this feature's score; w read after the NEXT barrier
        float s = spart;
        s += __shfl_xor(s, 1, 64);
        s += __shfl_xor(s, 2, 64);
        s += __shfl_xor(s, 4, 64);
        if ((tid & 7) == 0)
            wAll[FI * MTILE + (tid >> 3)] = __expf(s);   // scores ~N(0,1/3): no max-sub
    }
}

template<int FI>
__device__ __forceinline__ void fold(const float* wAll, f32x4 (&P)[2][2], f32x4 (&O)[2][2], int q4) {
    #pragma unroll
    for (int mt = 0; mt < 2; ++mt) {
        #pragma unroll
        for (int rr = 0; rr < 4; ++rr) {
            // C/D layout: col = lane&15, row = quad*4 + reg
            float w = wAll[FI * MTILE + mt * 16 + q4 * 4 + rr];
            O[mt][0][rr] += w * P[mt][0][rr];
            O[mt][1][rr] += w * P[mt][1][rr];
        }
    }
}

__global__ __launch_bounds__(THREADS, 4)
void attn_main(Ptrs p, const unsigned short* WvB, const float* qk,
               float* outC, float* outA) {
    __shared__ __align__(16) float Abuf[2 * MTILE * 128];   // 2 x 16 KB fp32 dbuf
    __shared__ float wAll[NFEAT * MTILE];
    __shared__ float Zrow[MTILE];
    float* buf0 = Abuf;
    float* buf1 = Abuf + MTILE * 128;

    int tid  = threadIdx.x;
    int wave = tid >> 6;
    int lane = tid & 63;
    int l15  = lane & 15, q4 = lane >> 4;
    int row0 = blockIdx.x * MTILE;

    f32x4 P[2][2], O[2][2];
    #pragma unroll
    for (int mt = 0; mt < 2; ++mt) {
        O[mt][0] = f32x4{0.f, 0.f, 0.f, 0.f};
        O[mt][1] = f32x4{0.f, 0.f, 0.f, 0.f};
    }
    float spart = 0.f;

#define STG(FI,D,CK0,DC,MASK,BUF)  stage<FI,D,CK0,DC,MASK>(p, row0, tid, BUF)
#define CMP(FI,FOFF,CK0,DC,MASK,FIRST,LAST,BUF) \
    compute_chunk<FI,FOFF,CK0,DC,MASK,FIRST,LAST>(BUF, WvB, qk, wAll, spart, P, tid, wave, l15, q4)
#define FOLD(FI) fold<FI>(wAll, P, O, q4)
#define BAR() __syncthreads()

    // chunks: f0:32 f1:64 f2:96 f3:128 f4:128+64 f5:128x2 f6:128x3 f7:128x4  (15 chunks)
    // pipeline: [barrier] -> DMA(c+1) -> fold(prev feature) -> compute(c) -> ...
    STG(0, 32,   0, 32,3, buf0);                        BAR();
    STG(1, 64,   0, 64,7, buf1);          CMP(0,   0,   0, 32,3,true ,true , buf0); BAR();
    STG(2, 96,   0, 96,3, buf0); FOLD(0); CMP(1,  32,   0, 64,7,true ,true , buf1); BAR();
    STG(3,128,   0,128,7, buf1); FOLD(1); CMP(2,  96,   0, 96,3,true ,true , buf0); BAR();
    STG(4,192,   0,128,7, buf0); FOLD(2); CMP(3, 192,   0,128,7,true ,true , buf1); BAR();
    STG(4,192, 128, 64,7, buf1); FOLD(3); CMP(4, 320,   0,128,7,true ,false, buf0); BAR();
    STG(5,256,   0,128,7, buf0);          CMP(4, 320, 128, 64,7,false,true , buf1); BAR();
    STG(5,256, 128,128,7, buf1); FOLD(4); CMP(5, 512,   0,128,7,true ,false, buf0); BAR();
    STG(6,384,   0,128,7, buf0);          CMP(5, 512, 128,128,7,false,true , buf1); BAR();
    STG(6,384, 128,128,7, buf1); FOLD(5); CMP(6, 768,   0,128,7,true ,false, buf0); BAR();
    STG(6,384, 256,128,7, buf0);          CMP(6, 768, 128,128,7,false,false, buf1); BAR();
    STG(7,512,   0,128,7, buf1);          CMP(6, 768, 256,128,7,false,true , buf0); BAR();
    STG(7,512, 128,128,7, buf0); FOLD(6); CMP(7,1152,   0,128,7,true ,false, buf1); BAR();
    STG(7,512, 256,128,7, buf1);          CMP(7,1152, 128,128,7,false,false, buf0); BAR();
    STG(7,512, 384,128,7, buf0);          CMP(7,1152, 256,128,7,false,false, buf1); BAR();
                                          CMP(7,1152, 384,128,7,false,true , buf0); BAR();
    FOLD(7);
    if (tid < MTILE) {
        float z = 0.f;
        #pragma unroll
        for (int f = 0; f < NFEAT; ++f) z += wAll[f * MTILE + tid];
        Zrow[tid] = 1.0f / z;
    }
    BAR();

    // ---- epilogue: transpose O through LDS (reuse Abuf), coalesced float4 stores ----
    float* Ctmp = Abuf;   // 32 x 132 fp32
    #pragma unroll
    for (int mt = 0; mt < 2; ++mt) {
        #pragma unroll
        for (int rr = 0; rr < 4; ++rr) {
            int row = mt * 16 + q4 * 4 + rr;
            float zi = Zrow[row];
            Ctmp[row * 132 + wave * 32 + l15]      = O[mt][0][rr] * zi;
            Ctmp[row * 132 + wave * 32 + 16 + l15] = O[mt][1][rr] * zi;
        }
    }
    BAR();
    #pragma unroll
    for (int it = 0; it < 4; ++it) {
        int j = tid + it * THREADS;        // 0..1023 = 32 rows x 32 float4
        int r = j >> 5, c4 = (j & 31) * 4;
        *reinterpret_cast<float4*>(outC + (size_t)(row0 + r) * HID + c4) =
            *reinterpret_cast<const float4*>(Ctmp + r * 132 + c4);
    }
    if (tid < MTILE) {
        float zi = Zrow[tid];
        float4 a0, a1;
        a0.x = wAll[0 * MTILE + tid] * zi; a0.y = wAll[1 * MTILE + tid] * zi;
        a0.z = wAll[2 * MTILE + tid] * zi; a0.w = wAll[3 * MTILE + tid] * zi;
        a1.x = wAll[4 * MTILE + tid] * zi; a1.y = wAll[5 * MTILE + tid] * zi;
        a1.z = wAll[6 * MTILE + tid] * zi; a1.w = wAll[7 * MTILE + tid] * zi;
        float* dst = outA + (size_t)(row0 + tid) * NFEAT;
        *reinterpret_cast<float4*>(dst)     = a0;
        *reinterpret_cast<float4*>(dst + 4) = a1;
    }
#undef STG
#undef CMP
#undef FOLD
#undef BAR
}

extern "C" void kernel_launch(void* const* d_in, const int* in_sizes, int n_in,
                              void* d_out, int out_size, void* d_ws, size_t ws_size,
                              hipStream_t stream) {
    Ptrs p;
    // setup_inputs() dict order: feat0..feat7, then Wk0,Wv0,Wk1,Wv1,... (interleaved), then query
    for (int i = 0; i < NFEAT; ++i) {
        p.feat[i] = (const float*)d_in[i];
        p.wk[i]   = (const float*)d_in[NFEAT + 2 * i];
        p.wv[i]   = (const float*)d_in[NFEAT + 2 * i + 1];
    }
    p.q = (const float*)d_in[3 * NFEAT];

    // workspace: [WvB bf16: 128*1664*2 B][qk fp32: 1664*4 B]
    unsigned short* WvB = (unsigned short*)d_ws;
    float* qk = (float*)((char*)d_ws + 128 * 1664 * 2);

    prep_wv<<<NFEAT * 8, 256, 0, stream>>>(p, WvB);
    prep_qk<<<NFEAT, 256, 0, stream>>>(p, qk);

    float* outC = (float*)d_out;
    float* outA = outC + (size_t)BATCH * HID;
    attn_main<<<BATCH / MTILE, THREADS, 0, stream>>>(p, WvB, qk, outC, outA);
}